// Round 11
// baseline (160.379 us; speedup 1.0000x reference)
//
#include <hip/hip_runtime.h>
#include <stdint.h>

#define NBATCH 2
#define LL 4096
#define CC 256
#define KEXP 0.09016844f   // (1/16) * log2(e)  : exp(acc/16) = exp2(acc*KEXP)
#define KEXP2 0.18033688f  // (2/16) * log2(e)
#define IMIN (-2147483647 - 1)

typedef long i64f;
typedef float f32x4 __attribute__((ext_vector_type(4)));

#if defined(__has_builtin) && __has_builtin(__builtin_amdgcn_exp2f)
#define EXP2F(x) __builtin_amdgcn_exp2f(x)
#else
#define EXP2F(x) exp2f(x)
#endif

// ---------------- cast fp32 -> fp8 e4m3 (OCP, HW packer) ----------------
__global__ __launch_bounds__(256) void cast_fp8(
    const float* __restrict__ a, const float* __restrict__ b,
    uint32_t* __restrict__ oa, uint32_t* __restrict__ ob){
  int idx = blockIdx.x * 256 + threadIdx.x;   // one uint32 = 4 fp8 per thread
  float4 va = ((const float4*)a)[idx];
  float4 vb = ((const float4*)b)[idx];
  int ra = __builtin_amdgcn_cvt_pk_fp8_f32(va.x, va.y, 0, false);
  ra = __builtin_amdgcn_cvt_pk_fp8_f32(va.z, va.w, ra, true);
  int rb = __builtin_amdgcn_cvt_pk_fp8_f32(vb.x, vb.y, 0, false);
  rb = __builtin_amdgcn_cvt_pk_fp8_f32(vb.z, vb.w, rb, true);
  oa[idx] = (uint32_t)ra;
  ob[idx] = (uint32_t)rb;
}

// ---------------- single conf pass: fp8 128x128, XOR-swizzled 32 KB LDS -----
// 8B chunk kg of row r stored at kg ^ (r & 15): b64 frag reads hit 16 distinct
// bank-pairs per quad (minimal 4 acc/bank for b64), LDS = 32 KB -> 5 blocks/CU.
// Emits per-(lt,st) partials: row/col exp-sums and row/col argmax as packed
// keys ((int)(acc*2048)<<12 | 12-bit idx). Epilogue scratch overlays Alds.
// C/D layout [m89]: l = lq*64+r*16+quad*4+rr, s = sq*64+j*16+lr
__global__ __launch_bounds__(256, 5) void conf_pass(
    const uint8_t* __restrict__ f0q, const uint8_t* __restrict__ f1q,
    float* __restrict__ rowSum, float* __restrict__ colSum,
    int* __restrict__ rowPart, int* __restrict__ colPart){
  __shared__ uint8_t Alds[128*128], Blds[128*128];
  float* rowS = (float*)Alds;            // [2][128] overlay (valid after MFMA)
  float* colS = (float*)(Alds + 1024);   // [2][128]
  int*   rb   = (int*)  (Alds + 2048);   // [2][128]
  int*   cb   = (int*)  (Alds + 3072);   // [2][128]
  int st = blockIdx.x, lt = blockIdx.y, n = blockIdx.z;
  int t = threadIdx.x;
  const int wv = t >> 6, lane = t & 63, lr = lane & 15, quad = lane >> 4;
  const int lq = wv >> 1, sq = wv & 1;
  const uint8_t* A = f0q + (size_t)n*LL*CC;
  const uint8_t* B = f1q + (size_t)n*LL*CC;
  f32x4 acc[4][4];
  #pragma unroll
  for (int r = 0; r < 4; r++)
    #pragma unroll
    for (int j = 0; j < 4; j++) acc[r][j] = (f32x4){0.f,0.f,0.f,0.f};
  for (int kc = 0; kc < 2; kc++){
    __syncthreads();
    #pragma unroll
    for (int m = 0; m < 8; m++){
      int f = m*256 + t, row = f >> 4, kg = f & 15;   // 8B chunks, 16/row
      int dst = row*128 + ((kg ^ (row & 15)) << 3);   // XOR swizzle
      *(uint2*)(Alds + dst) =
          *(const uint2*)(A + (size_t)(lt*128 + row)*CC + kc*128 + kg*8);
      *(uint2*)(Blds + dst) =
          *(const uint2*)(B + (size_t)(st*128 + row)*CC + kc*128 + kg*8);
    }
    __syncthreads();
    #pragma unroll
    for (int kk = 0; kk < 4; kk++){
      i64f a[4], b[4];
      int csw = (kk*4 + quad) ^ lr;                   // row&15 == lr for frags
      #pragma unroll
      for (int r = 0; r < 4; r++)
        a[r] = *(const i64f*)(Alds + (lq*64 + r*16 + lr)*128 + (csw << 3));
      #pragma unroll
      for (int j = 0; j < 4; j++)
        b[j] = *(const i64f*)(Blds + (sq*64 + j*16 + lr)*128 + (csw << 3));
      #pragma unroll
      for (int r = 0; r < 4; r++)
        #pragma unroll
        for (int j = 0; j < 4; j++)
          acc[r][j] = __builtin_amdgcn_mfma_f32_16x16x32_fp8_fp8(a[r], b[j], acc[r][j], 0, 0, 0);
    }
  }
  // ---- epilogue: exp-sums + packed argmax keys (registers + shuffles) ----
  const int sbase = st*128 + sq*64 + lr;        // + j*16
  const int lbase = lt*128 + lq*64 + quad*4;    // + r*16 + rr
  float rsum[4][4], csum[4] = {0.f,0.f,0.f,0.f};
  int rkey[4][4], ckey[4] = {IMIN,IMIN,IMIN,IMIN};
  #pragma unroll
  for (int r = 0; r < 4; r++)
    #pragma unroll
    for (int rr = 0; rr < 4; rr++){ rsum[r][rr] = 0.f; rkey[r][rr] = IMIN; }
  #pragma unroll
  for (int r = 0; r < 4; r++)
    #pragma unroll
    for (int j = 0; j < 4; j++)
      #pragma unroll
      for (int rr = 0; rr < 4; rr++){
        float a = acc[r][j][rr];
        float e = EXP2F(a * KEXP);
        rsum[r][rr] += e;
        csum[j] += e;
        int iqs = ((int)(a * 2048.f)) << 12;
        rkey[r][rr] = max(rkey[r][rr], iqs + (sbase + j*16));
        ckey[j]     = max(ckey[j],     iqs + (lbase + r*16 + rr));
      }
  #pragma unroll
  for (int msk = 1; msk <= 8; msk <<= 1)
    #pragma unroll
    for (int r = 0; r < 4; r++)
      #pragma unroll
      for (int rr = 0; rr < 4; rr++){
        rsum[r][rr] += __shfl_xor(rsum[r][rr], msk);
        rkey[r][rr] = max(rkey[r][rr], __shfl_xor(rkey[r][rr], msk));
      }
  #pragma unroll
  for (int msk = 16; msk <= 32; msk <<= 1)
    #pragma unroll
    for (int j = 0; j < 4; j++){
      csum[j] += __shfl_xor(csum[j], msk);
      ckey[j] = max(ckey[j], __shfl_xor(ckey[j], msk));
    }
  __syncthreads();   // all waves done reading tile LDS -> overlay is safe
  if (lr == 0){
    #pragma unroll
    for (int r = 0; r < 4; r++)
      #pragma unroll
      for (int rr = 0; rr < 4; rr++){
        int row = lq*64 + r*16 + quad*4 + rr;
        rowS[sq*128 + row] = rsum[r][rr];   // single writer per slot
        rb[sq*128 + row]   = rkey[r][rr];
      }
  }
  if (quad == 0){
    #pragma unroll
    for (int j = 0; j < 4; j++){
      int col = sq*64 + j*16 + lr;
      colS[lq*128 + col] = csum[j];
      cb[lq*128 + col]   = ckey[j];
    }
  }
  __syncthreads();
  if (t < 128){
    rowSum[((size_t)n*LL + lt*128 + t)*32 + st] = rowS[t] + rowS[128 + t];
    colSum[((size_t)n*LL + st*128 + t)*32 + lt] = colS[t] + colS[128 + t];
    rowPart[((size_t)n*LL + lt*128 + t)*32 + st] = max(rb[t], rb[128 + t]);
    colPart[((size_t)n*LL + st*128 + t)*32 + lt] = max(cb[t], cb[128 + t]);
  }
}

// ---------------- on-the-fly fea for the rare mask hit ----------------
__device__ float fea_fly(const float* __restrict__ featn, int srow, int t){
  __shared__ float sred[9][4];
  __shared__ float ssem[9];
  int lane = t & 63, wv = t >> 6;
  int h = srow >> 6, xx = srow & 63;
  float fv = featn[(size_t)srow * CC + t];
  float uv[9];
  #pragma unroll
  for (int w = 0; w < 9; w++){
    int dy = w/3 - 1, dx = w%3 - 1;
    int y = h + dy, x = xx + dx;
    uv[w] = (y >= 0 && y < 64 && x >= 0 && x < 64) ? featn[(size_t)t * 4096 + y*64 + x] : 0.f;
  }
  __syncthreads();
  #pragma unroll
  for (int w = 0; w < 9; w++){
    float pvv = fv * uv[w];
    #pragma unroll
    for (int msk = 1; msk <= 32; msk <<= 1) pvv += __shfl_xor(pvv, msk);
    if (lane == 0) sred[w][wv] = pvv;
  }
  __syncthreads();
  if (t < 9) ssem[t] = (sred[t][0] + sred[t][1] + sred[t][2] + sred[t][3]) * (1.f/256.f);
  __syncthreads();
  float acc = 0.f;
  #pragma unroll
  for (int w = 0; w < 9; w++) acc += uv[w] * ssem[w];
  __syncthreads();
  return acc;
}

__device__ __forceinline__ float pool_window(const float* f, const float* s, int t){
  if (t < 160){
    int a = (t*8)/5, e = (t*8+12)/5;
    float sum = 0.f;
    for (int i = a; i < e; i++) sum += f[i];
    return sum / (float)(e - a);
  } else {
    int tt = t - 160;
    int a = (tt*8)/3, e = (tt*8+10)/3;
    float sum = 0.f;
    for (int i = a; i < e; i++) sum += s[i];
    return sum / (float)(e - a);
  }
}

// ---------------- fused tail: partial reduce + mutual-NN + pool + LN --------
__global__ __launch_bounds__(256) void tail(
    const float* __restrict__ feat0, const float* __restrict__ feat1,
    const float* __restrict__ rowSum, const float* __restrict__ colSum,
    const int* __restrict__ rowPart, const int* __restrict__ colPart,
    const float* __restrict__ lnw, const float* __restrict__ lnb,
    float* __restrict__ out){
  int l = blockIdx.x, n = blockIdx.y, t = threadIdx.x;
  int lane = t & 63, wv = t >> 6;
  size_t base = (size_t)n * LL;
  __shared__ float sVal[8];   // [R_l, C_l, rowK, colK, C_ssr, R_ssc, ck2, rk2]
  // ---- phase 1 ----
  {
    float s = 0.f; int k = IMIN;
    if (lane < 32){
      size_t off = (base + l)*32 + lane;
      if      (wv == 0) s = rowSum[off];
      else if (wv == 1) s = colSum[off];
      else if (wv == 2) k = rowPart[off];
      else              k = colPart[off];
    }
    #pragma unroll
    for (int msk = 1; msk <= 16; msk <<= 1){
      s += __shfl_xor(s, msk);
      k = max(k, __shfl_xor(k, msk));
    }
    if (lane == 0) sVal[wv] = (wv < 2) ? s : __int_as_float(k);
  }
  __syncthreads();
  int rowK = __float_as_int(sVal[2]), colK = __float_as_int(sVal[3]);
  int ssr = rowK & 4095, ssc = colK & 4095;
  // ---- phase 2 ----
  {
    float s = 0.f; int k = IMIN;
    if (lane < 32){
      if      (wv == 0) s = colSum [(base + ssr)*32 + lane];
      else if (wv == 1) s = rowSum [(base + ssc)*32 + lane];
      else if (wv == 2) k = colPart[(base + ssr)*32 + lane];
      else              k = rowPart[(base + ssc)*32 + lane];
    }
    #pragma unroll
    for (int msk = 1; msk <= 16; msk <<= 1){
      s += __shfl_xor(s, msk);
      k = max(k, __shfl_xor(k, msk));
    }
    if (lane == 0) sVal[4 + wv] = (wv < 2) ? s : __int_as_float(k);
  }
  __syncthreads();
  float Rl   = sVal[0], Cl   = sVal[1];
  float Cssr = sVal[4], Rssc = sVal[5];
  int ck2 = __float_as_int(sVal[6]), rk2 = __float_as_int(sVal[7]);
  float v0 = 0.f, v1 = 0.f;
  {
    float araw = (float)(rowK >> 12) * (1.f/2048.f);
    float val = exp2f(araw * KEXP2) / (Rl * Cssr);   // conf'(l,ssr)
    if (val > 0.2f && (ck2 & 4095) == l)
      v0 = fea_fly(feat1 + (size_t)n*LL*CC, ssr, t) * (1.f/4096.f);
  }
  {
    float araw = (float)(colK >> 12) * (1.f/2048.f);
    float val = exp2f(araw * KEXP2) / (Cl * Rssc);   // conf'(ssc,l)
    if (val > 0.2f && (rk2 & 4095) == l)
      v1 = fea_fly(feat0 + (size_t)n*LL*CC, ssc, t) * (1.f/4096.f);
  }
  // ---- pool + LN ----
  __shared__ float f0r[CC], f1r[CC], s0r[CC], s1r[CC];
  __shared__ float redA[2][4], redB[2][4];
  f0r[t] = feat0[(base + l)*CC + t];
  f1r[t] = feat1[(base + l)*CC + t];
  s0r[t] = v0;
  s1r[t] = v1;
  __syncthreads();
  float pA = pool_window(f0r, s0r, t);
  float pB = pool_window(f1r, s1r, t);
  float smA = pA, sqA = pA*pA, smB = pB, sqB = pB*pB;
  #pragma unroll
  for (int msk = 1; msk <= 32; msk <<= 1){
    smA += __shfl_xor(smA, msk);
    sqA += __shfl_xor(sqA, msk);
    smB += __shfl_xor(smB, msk);
    sqB += __shfl_xor(sqB, msk);
  }
  if (lane == 0){ redA[0][wv] = smA; redA[1][wv] = sqA; redB[0][wv] = smB; redB[1][wv] = sqB; }
  __syncthreads();
  float tsA = redA[0][0]+redA[0][1]+redA[0][2]+redA[0][3];
  float tqA = redA[1][0]+redA[1][1]+redA[1][2]+redA[1][3];
  float tsB = redB[0][0]+redB[0][1]+redB[0][2]+redB[0][3];
  float tqB = redB[1][0]+redB[1][1]+redB[1][2]+redB[1][3];
  float muA = tsA * (1.f/256.f), varA = tqA * (1.f/256.f) - muA*muA;
  float muB = tsB * (1.f/256.f), varB = tqB * (1.f/256.f) - muB*muB;
  float w = lnw[t], bsh = lnb[t];
  out[((size_t)n*LL + l)*CC + t]       = (pA - muA) * rsqrtf(varA + 1e-5f) * w + bsh;
  out[((size_t)(2 + n)*LL + l)*CC + t] = (pB - muB) * rsqrtf(varB + 1e-5f) * w + bsh;
}

extern "C" void kernel_launch(void* const* d_in, const int* in_sizes, int n_in,
                              void* d_out, int out_size, void* d_ws, size_t ws_size,
                              hipStream_t stream){
  const float* feat0 = (const float*)d_in[0];
  const float* feat1 = (const float*)d_in[1];
  const float* lnw   = (const float*)d_in[2];
  const float* lnb   = (const float*)d_in[3];
  float* out = (float*)d_out;
  char* ws = (char*)d_ws;
  const size_t MB = 1024 * 1024;
  uint8_t* f0q = (uint8_t*)(ws + 0);        // 2 MB fp8
  uint8_t* f1q = (uint8_t*)(ws + 2*MB);     // 2 MB fp8
  float* rowSum  = (float*)(ws + 4*MB);     // [8192][32] = 1 MB
  float* colSum  = (float*)(ws + 5*MB);     // 1 MB
  int*   rowPart = (int*)  (ws + 6*MB);     // 1 MB
  int*   colPart = (int*)  (ws + 7*MB);     // 1 MB

  cast_fp8<<<2048, 256, 0, stream>>>(feat0, feat1, (uint32_t*)f0q, (uint32_t*)f1q);
  dim3 gconf(32, 32, NBATCH);
  conf_pass<<<gconf, 256, 0, stream>>>(f0q, f1q, rowSum, colSum, rowPart, colPart);
  dim3 gt(LL, NBATCH);
  tail<<<gt, 256, 0, stream>>>(feat0, feat1, rowSum, colSum, rowPart, colPart,
                               lnw, lnb, out);
}

// Round 12
// 135.274 us; speedup vs baseline: 1.1856x; 1.1856x over previous
//
#include <hip/hip_runtime.h>
#include <stdint.h>

#define NBATCH 2
#define LL 4096
#define CC 256
#define LSTR8 144      // fp8 LDS row stride (bytes): 128+16 -> b64 frag reads 2-way/free
#define KEXP 0.09016844f   // (1/16) * log2(e)  : exp(acc/16) = exp2(acc*KEXP)
#define KEXP2 0.18033688f  // (2/16) * log2(e)
#define IMIN (-2147483647 - 1)

typedef long i64f;
typedef float f32x4 __attribute__((ext_vector_type(4)));

#if defined(__has_builtin) && __has_builtin(__builtin_amdgcn_exp2f)
#define EXP2F(x) __builtin_amdgcn_exp2f(x)
#else
#define EXP2F(x) exp2f(x)
#endif

// ---------------- cast fp32 -> fp8 e4m3 (OCP, HW packer) ----------------
__global__ __launch_bounds__(256) void cast_fp8(
    const float* __restrict__ a, const float* __restrict__ b,
    uint32_t* __restrict__ oa, uint32_t* __restrict__ ob){
  int idx = blockIdx.x * 256 + threadIdx.x;   // one uint32 = 4 fp8 per thread
  float4 va = ((const float4*)a)[idx];
  float4 vb = ((const float4*)b)[idx];
  int ra = __builtin_amdgcn_cvt_pk_fp8_f32(va.x, va.y, 0, false);
  ra = __builtin_amdgcn_cvt_pk_fp8_f32(va.z, va.w, ra, true);
  int rb = __builtin_amdgcn_cvt_pk_fp8_f32(vb.x, vb.y, 0, false);
  rb = __builtin_amdgcn_cvt_pk_fp8_f32(vb.z, vb.w, rb, true);
  oa[idx] = (uint32_t)ra;
  ob[idx] = (uint32_t)rb;
}

// ---------------- single conf pass: fp8 128x128, 2 K-chunks, 4 barriers -----
// R10 configuration — verified best (no spill: VGPR~100, LDS 36.9 KB, 4 blk/CU).
// Emits per-(lt,st) partials: row/col exp-sums and row/col argmax as packed
// keys ((int)(acc*2048)<<12 | 12-bit idx). Epilogue scratch overlays Alds.
// C/D layout [m89]: l = lq*64+r*16+quad*4+rr, s = sq*64+j*16+lr
__global__ __launch_bounds__(256) void conf_pass(
    const uint8_t* __restrict__ f0q, const uint8_t* __restrict__ f1q,
    float* __restrict__ rowSum, float* __restrict__ colSum,
    int* __restrict__ rowPart, int* __restrict__ colPart){
  __shared__ uint8_t Alds[128*LSTR8], Blds[128*LSTR8];
  float* rowS = (float*)Alds;            // [2][128] overlay (valid after MFMA)
  float* colS = (float*)(Alds + 1024);   // [2][128]
  int*   rb   = (int*)  (Alds + 2048);   // [2][128]
  int*   cb   = (int*)  (Alds + 3072);   // [2][128]
  int st = blockIdx.x, lt = blockIdx.y, n = blockIdx.z;
  int t = threadIdx.x;
  const int wv = t >> 6, lane = t & 63, lr = lane & 15, quad = lane >> 4;
  const int lq = wv >> 1, sq = wv & 1;
  const uint8_t* A = f0q + (size_t)n*LL*CC;
  const uint8_t* B = f1q + (size_t)n*LL*CC;
  f32x4 acc[4][4];
  #pragma unroll
  for (int r = 0; r < 4; r++)
    #pragma unroll
    for (int j = 0; j < 4; j++) acc[r][j] = (f32x4){0.f,0.f,0.f,0.f};
  for (int kc = 0; kc < 2; kc++){
    __syncthreads();
    #pragma unroll
    for (int m = 0; m < 8; m++){
      int f = m*256 + t, row = f >> 4, kg = f & 15;   // 8B chunks, 16 per 128B row
      *(uint2*)(Alds + row*LSTR8 + kg*8) =
          *(const uint2*)(A + (size_t)(lt*128 + row)*CC + kc*128 + kg*8);
      *(uint2*)(Blds + row*LSTR8 + kg*8) =
          *(const uint2*)(B + (size_t)(st*128 + row)*CC + kc*128 + kg*8);
    }
    __syncthreads();
    #pragma unroll
    for (int kk = 0; kk < 4; kk++){
      i64f a[4], b[4];
      #pragma unroll
      for (int r = 0; r < 4; r++)
        a[r] = *(const i64f*)(Alds + (lq*64 + r*16 + lr)*LSTR8 + kk*32 + quad*8);
      #pragma unroll
      for (int j = 0; j < 4; j++)
        b[j] = *(const i64f*)(Blds + (sq*64 + j*16 + lr)*LSTR8 + kk*32 + quad*8);
      #pragma unroll
      for (int r = 0; r < 4; r++)
        #pragma unroll
        for (int j = 0; j < 4; j++)
          acc[r][j] = __builtin_amdgcn_mfma_f32_16x16x32_fp8_fp8(a[r], b[j], acc[r][j], 0, 0, 0);
    }
  }
  // ---- epilogue: exp-sums + packed argmax keys (registers + shuffles) ----
  const int sbase = st*128 + sq*64 + lr;        // + j*16
  const int lbase = lt*128 + lq*64 + quad*4;    // + r*16 + rr
  float rsum[4][4], csum[4] = {0.f,0.f,0.f,0.f};
  int rkey[4][4], ckey[4] = {IMIN,IMIN,IMIN,IMIN};
  #pragma unroll
  for (int r = 0; r < 4; r++)
    #pragma unroll
    for (int rr = 0; rr < 4; rr++){ rsum[r][rr] = 0.f; rkey[r][rr] = IMIN; }
  #pragma unroll
  for (int r = 0; r < 4; r++)
    #pragma unroll
    for (int j = 0; j < 4; j++)
      #pragma unroll
      for (int rr = 0; rr < 4; rr++){
        float a = acc[r][j][rr];
        float e = EXP2F(a * KEXP);
        rsum[r][rr] += e;
        csum[j] += e;
        int iqs = ((int)(a * 2048.f)) << 12;
        rkey[r][rr] = max(rkey[r][rr], iqs + (sbase + j*16));
        ckey[j]     = max(ckey[j],     iqs + (lbase + r*16 + rr));
      }
  #pragma unroll
  for (int msk = 1; msk <= 8; msk <<= 1)
    #pragma unroll
    for (int r = 0; r < 4; r++)
      #pragma unroll
      for (int rr = 0; rr < 4; rr++){
        rsum[r][rr] += __shfl_xor(rsum[r][rr], msk);
        rkey[r][rr] = max(rkey[r][rr], __shfl_xor(rkey[r][rr], msk));
      }
  #pragma unroll
  for (int msk = 16; msk <= 32; msk <<= 1)
    #pragma unroll
    for (int j = 0; j < 4; j++){
      csum[j] += __shfl_xor(csum[j], msk);
      ckey[j] = max(ckey[j], __shfl_xor(ckey[j], msk));
    }
  __syncthreads();   // all waves done reading tile LDS -> overlay is safe
  if (lr == 0){
    #pragma unroll
    for (int r = 0; r < 4; r++)
      #pragma unroll
      for (int rr = 0; rr < 4; rr++){
        int row = lq*64 + r*16 + quad*4 + rr;
        rowS[sq*128 + row] = rsum[r][rr];   // single writer per slot
        rb[sq*128 + row]   = rkey[r][rr];
      }
  }
  if (quad == 0){
    #pragma unroll
    for (int j = 0; j < 4; j++){
      int col = sq*64 + j*16 + lr;
      colS[lq*128 + col] = csum[j];
      cb[lq*128 + col]   = ckey[j];
    }
  }
  __syncthreads();
  if (t < 128){
    rowSum[((size_t)n*LL + lt*128 + t)*32 + st] = rowS[t] + rowS[128 + t];
    colSum[((size_t)n*LL + st*128 + t)*32 + lt] = colS[t] + colS[128 + t];
    rowPart[((size_t)n*LL + lt*128 + t)*32 + st] = max(rb[t], rb[128 + t]);
    colPart[((size_t)n*LL + st*128 + t)*32 + lt] = max(cb[t], cb[128 + t]);
  }
}

// ---------------- on-the-fly fea for the rare mask hit ----------------
__device__ float fea_fly(const float* __restrict__ featn, int srow, int t){
  __shared__ float sred[9][4];
  __shared__ float ssem[9];
  int lane = t & 63, wv = t >> 6;
  int h = srow >> 6, xx = srow & 63;
  float fv = featn[(size_t)srow * CC + t];
  float uv[9];
  #pragma unroll
  for (int w = 0; w < 9; w++){
    int dy = w/3 - 1, dx = w%3 - 1;
    int y = h + dy, x = xx + dx;
    uv[w] = (y >= 0 && y < 64 && x >= 0 && x < 64) ? featn[(size_t)t * 4096 + y*64 + x] : 0.f;
  }
  __syncthreads();
  #pragma unroll
  for (int w = 0; w < 9; w++){
    float pvv = fv * uv[w];
    #pragma unroll
    for (int msk = 1; msk <= 32; msk <<= 1) pvv += __shfl_xor(pvv, msk);
    if (lane == 0) sred[w][wv] = pvv;
  }
  __syncthreads();
  if (t < 9) ssem[t] = (sred[t][0] + sred[t][1] + sred[t][2] + sred[t][3]) * (1.f/256.f);
  __syncthreads();
  float acc = 0.f;
  #pragma unroll
  for (int w = 0; w < 9; w++) acc += uv[w] * ssem[w];
  __syncthreads();
  return acc;
}

__device__ __forceinline__ float pool_window(const float* f, const float* s, int t){
  if (t < 160){
    int a = (t*8)/5, e = (t*8+12)/5;
    float sum = 0.f;
    for (int i = a; i < e; i++) sum += f[i];
    return sum / (float)(e - a);
  } else {
    int tt = t - 160;
    int a = (tt*8)/3, e = (tt*8+10)/3;
    float sum = 0.f;
    for (int i = a; i < e; i++) sum += s[i];
    return sum / (float)(e - a);
  }
}

// ---------------- fused tail: partial reduce + mutual-NN + pool + LN --------
__global__ __launch_bounds__(256) void tail(
    const float* __restrict__ feat0, const float* __restrict__ feat1,
    const float* __restrict__ rowSum, const float* __restrict__ colSum,
    const int* __restrict__ rowPart, const int* __restrict__ colPart,
    const float* __restrict__ lnw, const float* __restrict__ lnb,
    float* __restrict__ out){
  int l = blockIdx.x, n = blockIdx.y, t = threadIdx.x;
  int lane = t & 63, wv = t >> 6;
  size_t base = (size_t)n * LL;
  __shared__ float sVal[8];   // [R_l, C_l, rowK, colK, C_ssr, R_ssc, ck2, rk2]
  // ---- phase 1 ----
  {
    float s = 0.f; int k = IMIN;
    if (lane < 32){
      size_t off = (base + l)*32 + lane;
      if      (wv == 0) s = rowSum[off];
      else if (wv == 1) s = colSum[off];
      else if (wv == 2) k = rowPart[off];
      else              k = colPart[off];
    }
    #pragma unroll
    for (int msk = 1; msk <= 16; msk <<= 1){
      s += __shfl_xor(s, msk);
      k = max(k, __shfl_xor(k, msk));
    }
    if (lane == 0) sVal[wv] = (wv < 2) ? s : __int_as_float(k);
  }
  __syncthreads();
  int rowK = __float_as_int(sVal[2]), colK = __float_as_int(sVal[3]);
  int ssr = rowK & 4095, ssc = colK & 4095;
  // ---- phase 2 ----
  {
    float s = 0.f; int k = IMIN;
    if (lane < 32){
      if      (wv == 0) s = colSum [(base + ssr)*32 + lane];
      else if (wv == 1) s = rowSum [(base + ssc)*32 + lane];
      else if (wv == 2) k = colPart[(base + ssr)*32 + lane];
      else              k = rowPart[(base + ssc)*32 + lane];
    }
    #pragma unroll
    for (int msk = 1; msk <= 16; msk <<= 1){
      s += __shfl_xor(s, msk);
      k = max(k, __shfl_xor(k, msk));
    }
    if (lane == 0) sVal[4 + wv] = (wv < 2) ? s : __int_as_float(k);
  }
  __syncthreads();
  float Rl   = sVal[0], Cl   = sVal[1];
  float Cssr = sVal[4], Rssc = sVal[5];
  int ck2 = __float_as_int(sVal[6]), rk2 = __float_as_int(sVal[7]);
  float v0 = 0.f, v1 = 0.f;
  {
    float araw = (float)(rowK >> 12) * (1.f/2048.f);
    float val = exp2f(araw * KEXP2) / (Rl * Cssr);   // conf'(l,ssr)
    if (val > 0.2f && (ck2 & 4095) == l)
      v0 = fea_fly(feat1 + (size_t)n*LL*CC, ssr, t) * (1.f/4096.f);
  }
  {
    float araw = (float)(colK >> 12) * (1.f/2048.f);
    float val = exp2f(araw * KEXP2) / (Cl * Rssc);   // conf'(ssc,l)
    if (val > 0.2f && (rk2 & 4095) == l)
      v1 = fea_fly(feat0 + (size_t)n*LL*CC, ssc, t) * (1.f/4096.f);
  }
  // ---- pool + LN ----
  __shared__ float f0r[CC], f1r[CC], s0r[CC], s1r[CC];
  __shared__ float redA[2][4], redB[2][4];
  f0r[t] = feat0[(base + l)*CC + t];
  f1r[t] = feat1[(base + l)*CC + t];
  s0r[t] = v0;
  s1r[t] = v1;
  __syncthreads();
  float pA = pool_window(f0r, s0r, t);
  float pB = pool_window(f1r, s1r, t);
  float smA = pA, sqA = pA*pA, smB = pB, sqB = pB*pB;
  #pragma unroll
  for (int msk = 1; msk <= 32; msk <<= 1){
    smA += __shfl_xor(smA, msk);
    sqA += __shfl_xor(sqA, msk);
    smB += __shfl_xor(smB, msk);
    sqB += __shfl_xor(sqB, msk);
  }
  if (lane == 0){ redA[0][wv] = smA; redA[1][wv] = sqA; redB[0][wv] = smB; redB[1][wv] = sqB; }
  __syncthreads();
  float tsA = redA[0][0]+redA[0][1]+redA[0][2]+redA[0][3];
  float tqA = redA[1][0]+redA[1][1]+redA[1][2]+redA[1][3];
  float tsB = redB[0][0]+redB[0][1]+redB[0][2]+redB[0][3];
  float tqB = redB[1][0]+redB[1][1]+redB[1][2]+redB[1][3];
  float muA = tsA * (1.f/256.f), varA = tqA * (1.f/256.f) - muA*muA;
  float muB = tsB * (1.f/256.f), varB = tqB * (1.f/256.f) - muB*muB;
  float w = lnw[t], bsh = lnb[t];
  out[((size_t)n*LL + l)*CC + t]       = (pA - muA) * rsqrtf(varA + 1e-5f) * w + bsh;
  out[((size_t)(2 + n)*LL + l)*CC + t] = (pB - muB) * rsqrtf(varB + 1e-5f) * w + bsh;
}

extern "C" void kernel_launch(void* const* d_in, const int* in_sizes, int n_in,
                              void* d_out, int out_size, void* d_ws, size_t ws_size,
                              hipStream_t stream){
  const float* feat0 = (const float*)d_in[0];
  const float* feat1 = (const float*)d_in[1];
  const float* lnw   = (const float*)d_in[2];
  const float* lnb   = (const float*)d_in[3];
  float* out = (float*)d_out;
  char* ws = (char*)d_ws;
  const size_t MB = 1024 * 1024;
  uint8_t* f0q = (uint8_t*)(ws + 0);        // 2 MB fp8
  uint8_t* f1q = (uint8_t*)(ws + 2*MB);     // 2 MB fp8
  float* rowSum  = (float*)(ws + 4*MB);     // [8192][32] = 1 MB
  float* colSum  = (float*)(ws + 5*MB);     // 1 MB
  int*   rowPart = (int*)  (ws + 6*MB);     // 1 MB
  int*   colPart = (int*)  (ws + 7*MB);     // 1 MB

  cast_fp8<<<2048, 256, 0, stream>>>(feat0, feat1, (uint32_t*)f0q, (uint32_t*)f1q);
  dim3 gconf(32, 32, NBATCH);
  conf_pass<<<gconf, 256, 0, stream>>>(f0q, f1q, rowSum, colSum, rowPart, colPart);
  dim3 gt(LL, NBATCH);
  tail<<<gt, 256, 0, stream>>>(feat0, feat1, rowSum, colSum, rowPart, colPart,
                               lnw, lnb, out);
}